// Round 4
// baseline (86.062 us; speedup 1.0000x reference)
//
#include <hip/hip_runtime.h>

// ExodusNet: weighted = W[1,32] @ x[B,32,T] -> LIF scan over T -> spikes [B,1,T]
// B = 32768, F = 32, T = 100. All float32. Memory-bound (419 MB read, 13 MB write).
//
// R4: wave-independent restructure. Each wave owns RPW=8 batch rows and a
// private LDS slice; NO __syncthreads anywhere — phase ordering is enforced
// per-wave with s_waitcnt lgkmcnt(0) (LDS ops retire in wave order, and
// lgkmcnt is a per-wave counter, so 0 means all 64 lanes' ds_writes are
// visible). Waves drift out of phase, so scans/writebacks of some waves
// overlap global reads of others and the HBM pipe stays saturated.
//   Phase 1: wave computes weighted[8][100] (float4 over T, full-line
//            coalescing), f-loop split 2x16 to keep VGPR < 128.
//   Phase 2: lanes 0..7 run the serial 100-step LIF scan in LDS
//            (XOR-swizzled rows -> conflict-free b128).
//   Phase 3: wave stores spikes coalesced.

#define RPW    8               // batch rows per wave
#define WAVES  4
#define NB     (RPW * WAVES)   // 32 rows per block
#define BLOCK  256
#define TT     100
#define FF     32
#define T4     (TT / 4)        // 25 float4 groups per row
#define ROWPAD 128             // dwords per LDS row (32 float4 slots for t4^7)

__global__ __launch_bounds__(BLOCK) void exodus_lif_kernel(
        const float* __restrict__ x,
        const float* __restrict__ Wg,
        float* __restrict__ out)
{
    __shared__ __align__(16) float wbuf[NB * ROWPAD];  // 16 KB

    const int  tid  = threadIdx.x;
    const int  wv   = tid >> 6;
    const int  lane = tid & 63;
    const long b0   = (long)blockIdx.x * NB + wv * RPW;  // first global row of wave
    float* const wlds = &wbuf[(wv * RPW) * ROWPAD];      // wave-private LDS slice

    // ---- Phase 1: weighted[rl][t] = sum_f W[f] * x[b0+rl, f, t] ----
    const int NIT = RPW * T4;  // 200 float4 items per wave
    for (int i = lane; i < NIT; i += 64) {
        const int rl = i / T4;
        const int t4 = i % T4;
        const float4* xp =
            reinterpret_cast<const float4*>(x + (b0 + rl) * (long)(FF * TT) + t4 * 4);
        float4 a0 = make_float4(0.f, 0.f, 0.f, 0.f);
        float4 a1 = make_float4(0.f, 0.f, 0.f, 0.f);
#pragma unroll
        for (int f = 0; f < 16; ++f) {
            const float4 xv = xp[f * T4];
            const float  w  = Wg[f];
            a0.x += w * xv.x; a0.y += w * xv.y; a0.z += w * xv.z; a0.w += w * xv.w;
        }
#pragma unroll
        for (int f = 16; f < 32; ++f) {
            const float4 xv = xp[f * T4];
            const float  w  = Wg[f];
            a1.x += w * xv.x; a1.y += w * xv.y; a1.z += w * xv.z; a1.w += w * xv.w;
        }
        a0.x += a1.x; a0.y += a1.y; a0.z += a1.z; a0.w += a1.w;
        const int t4s = t4 ^ (rl & 7);  // bank swizzle
        *reinterpret_cast<float4*>(&wlds[rl * ROWPAD + t4s * 4]) = a0;
    }
    asm volatile("s_waitcnt lgkmcnt(0)" ::: "memory");  // wave's ds_writes visible

    // ---- Phase 2: sequential LIF scan, lanes 0..RPW-1, one row each ----
    if (lane < RPW) {
        const float A  = 0.90483741803595952f;  // exp(-1/10)
        const float OM = 0.09516258196404048f;  // 1 - A
        const int   rl = lane;
        float v = 0.f;
#pragma unroll
        for (int t4 = 0; t4 < T4; ++t4) {
            const int t4s = t4 ^ (rl & 7);
            float4 w = *reinterpret_cast<float4*>(&wlds[rl * ROWPAD + t4s * 4]);
            float* we = &w.x;
#pragma unroll
            for (int k = 0; k < 4; ++k) {
                v = A * v + OM * we[k];
                const float s = (v >= 1.0f) ? 1.0f : 0.0f;
                v -= s;
                we[k] = s;
            }
            *reinterpret_cast<float4*>(&wlds[rl * ROWPAD + t4s * 4]) = w;
        }
    }
    asm volatile("s_waitcnt lgkmcnt(0)" ::: "memory");  // scan results visible

    // ---- Phase 3: coalesced spike writeback ----
    for (int i = lane; i < NIT; i += 64) {
        const int rl  = i / T4;
        const int t4  = i % T4;
        const int t4s = t4 ^ (rl & 7);
        const float4 s = *reinterpret_cast<const float4*>(&wlds[rl * ROWPAD + t4s * 4]);
        *reinterpret_cast<float4*>(out + (b0 + rl) * (long)TT + t4 * 4) = s;
    }
}

extern "C" void kernel_launch(void* const* d_in, const int* in_sizes, int n_in,
                              void* d_out, int out_size, void* d_ws, size_t ws_size,
                              hipStream_t stream) {
    const float* x  = (const float*)d_in[0];   // [32768, 2, 4, 4, 100] = [B, 32, 100]
    const float* Wg = (const float*)d_in[1];   // [1, 32]
    float* out      = (float*)d_out;           // [32768, 1, 100]

    const int B    = in_sizes[0] / (FF * TT);  // 32768
    const int grid = B / NB;                   // 1024

    exodus_lif_kernel<<<grid, BLOCK, 0, stream>>>(x, Wg, out);
}